// Round 1
// baseline (559.047 us; speedup 1.0000x reference)
//
#include <hip/hip_runtime.h>

// MaxUnPooling2DArgMax: scatter-add pooled values into 2x-upsampled output.
// B=8, H=128, W=128, C=64, stride 2x2 -> out per batch = 256*256*64 = 2^22.
// In per batch = 128*128*64 = 2^20. Total in elems N = 2^23.
//
// Strategy: hipMemsetAsync zeroes d_out (harness re-poisons to 0xAA each
// timed call, so we must zero every launch). Then one kernel: 4 elems/thread
// via float4/int4 vector loads, 4 device-scope atomicAdds each. Output slab
// (134 MB) fits in L3, so atomics mostly hit L2/L3.

constexpr int IN_PER_BATCH_LOG2  = 20;  // 128*128*64
constexpr int OUT_PER_BATCH_LOG2 = 22;  // 256*256*64
constexpr int N = 8 << IN_PER_BATCH_LOG2;  // 8,388,608 input elements

__global__ __launch_bounds__(256) void unpool_scatter_kernel(
    const float4* __restrict__ in,
    const int4*   __restrict__ idx,
    float*        __restrict__ out) {
    int t = blockIdx.x * blockDim.x + threadIdx.x;  // one thread = 4 elements
    // 4*t is the flat element index; 4 consecutive elems share a batch
    // (batch size 2^20 divisible by 4). base = (4t >> 20) << 22 = (t>>18)<<22.
    float4 v  = in[t];
    int4   ix = idx[t];
    float* obase = out + ((size_t)(t >> (IN_PER_BATCH_LOG2 - 2)) << OUT_PER_BATCH_LOG2);
    atomicAdd(obase + ix.x, v.x);
    atomicAdd(obase + ix.y, v.y);
    atomicAdd(obase + ix.z, v.z);
    atomicAdd(obase + ix.w, v.w);
}

extern "C" void kernel_launch(void* const* d_in, const int* in_sizes, int n_in,
                              void* d_out, int out_size, void* d_ws, size_t ws_size,
                              hipStream_t stream) {
    const float4* in  = (const float4*)d_in[0];
    const int4*   idx = (const int4*)d_in[1];
    float*        out = (float*)d_out;

    // Zero the output every call (harness poisons it with 0xAA).
    hipMemsetAsync(d_out, 0, (size_t)out_size * sizeof(float), stream);

    const int threads = N / 4;            // 2,097,152
    const int block = 256;
    const int grid = threads / block;     // 8192 blocks
    unpool_scatter_kernel<<<grid, block, 0, stream>>>(in, idx, out);
}

// Round 2
// 328.204 us; speedup vs baseline: 1.7034x; 1.7034x over previous
//
#include <hip/hip_runtime.h>

// MaxUnPooling2DArgMax via two-phase binning (no device-scope fp32 atomics).
// B=8, in/batch=2^20, out/batch=2^22, N=2^23 pairs, out total 2^25 floats.
// Bin = 8192 floats (32 KB). 512 bins/batch, 4096 bins total.
// global_out = bin*8192 + off;  bin = (batch<<9) | (idx>>13);  off = idx&8191.

typedef unsigned int u32;

constexpr int N            = 1 << 23;   // input pairs
constexpr int NBINS        = 4096;
constexpr int BINS_PER_B   = 512;       // per batch
constexpr int BIN_FLOATS   = 8192;      // 32 KB
constexpr size_t PAIR_BYTES = (size_t)N * 8;

// ---------------- K1: histogram ----------------
// 256 blocks x 512 thr, chunk = 32768 pairs (32 blocks/batch), 16 int4/thread.
__global__ __launch_bounds__(512) void k1_hist(const int4* __restrict__ idx4,
                                               u32* __restrict__ hist) {
    __shared__ u32 lhist[BINS_PER_B];
    int tid = threadIdx.x;
    if (tid < BINS_PER_B) lhist[tid] = 0;
    __syncthreads();
    const int cb4 = blockIdx.x * 8192;              // 32768/4 int4 per block
    const u32 bb  = (u32)(blockIdx.x >> 5) << 9;    // batch * 512
#pragma unroll
    for (int i = 0; i < 16; ++i) {
        int4 v = idx4[cb4 + i * 512 + tid];
        atomicAdd(&lhist[(u32)v.x >> 13], 1u);
        atomicAdd(&lhist[(u32)v.y >> 13], 1u);
        atomicAdd(&lhist[(u32)v.z >> 13], 1u);
        atomicAdd(&lhist[(u32)v.w >> 13], 1u);
    }
    __syncthreads();
    if (tid < BINS_PER_B) {
        u32 c = lhist[tid];
        if (c) atomicAdd(&hist[bb + tid], c);
    }
}

// ---------------- K2: exclusive scan (1 wave) ----------------
__global__ void k2_scan(const u32* __restrict__ hist, u32* __restrict__ start,
                        u32* __restrict__ cursor) {
    int lane = threadIdx.x;  // blockDim = 64
    u32 base = 0;
    for (int c = 0; c < NBINS; c += 64) {
        u32 v = hist[c + lane];
        u32 s = v;
#pragma unroll
        for (int d = 1; d < 64; d <<= 1) {
            u32 t = __shfl_up(s, d);
            if (lane >= d) s += t;
        }
        u32 excl = base + (s - v);
        start[c + lane]  = excl;
        cursor[c + lane] = excl;
        base += __shfl(s, 63);
    }
}

// ---------------- K3: scatter pairs into bin lists ----------------
// 512 blocks x 512 thr, chunk = 16384 pairs (64 blocks/batch), 32 pairs/thread.
__global__ __launch_bounds__(512) void k3_scatter(const int4* __restrict__ idx4,
                                                  const float4* __restrict__ val4,
                                                  u32* __restrict__ cursor,
                                                  uint2* __restrict__ pairs) {
    __shared__ u32 lhist[BINS_PER_B];
    __shared__ u32 lbase[BINS_PER_B];
    int tid = threadIdx.x;
    if (tid < BINS_PER_B) lhist[tid] = 0;
    __syncthreads();
    const int cb4 = blockIdx.x * 4096;              // 16384/4 int4 per block
    const u32 bb  = (u32)(blockIdx.x >> 6) << 9;    // batch * 512
    // Pass A: local histogram
#pragma unroll
    for (int i = 0; i < 8; ++i) {
        int4 v = idx4[cb4 + i * 512 + tid];
        atomicAdd(&lhist[(u32)v.x >> 13], 1u);
        atomicAdd(&lhist[(u32)v.y >> 13], 1u);
        atomicAdd(&lhist[(u32)v.z >> 13], 1u);
        atomicAdd(&lhist[(u32)v.w >> 13], 1u);
    }
    __syncthreads();
    // Reserve global ranges, reset lhist as running offset
    if (tid < BINS_PER_B) {
        u32 c = lhist[tid];
        lbase[tid] = c ? atomicAdd(&cursor[bb + tid], c) : 0u;
        lhist[tid] = 0;
    }
    __syncthreads();
    // Pass B: write pairs
#pragma unroll
    for (int i = 0; i < 8; ++i) {
        int4   ix = idx4[cb4 + i * 512 + tid];
        float4 v  = val4[cb4 + i * 512 + tid];
        {
            u32 b = (u32)ix.x >> 13, r = atomicAdd(&lhist[b], 1u);
            pairs[lbase[b] + r] = make_uint2(__float_as_uint(v.x), (u32)ix.x & 8191u);
        }
        {
            u32 b = (u32)ix.y >> 13, r = atomicAdd(&lhist[b], 1u);
            pairs[lbase[b] + r] = make_uint2(__float_as_uint(v.y), (u32)ix.y & 8191u);
        }
        {
            u32 b = (u32)ix.z >> 13, r = atomicAdd(&lhist[b], 1u);
            pairs[lbase[b] + r] = make_uint2(__float_as_uint(v.z), (u32)ix.z & 8191u);
        }
        {
            u32 b = (u32)ix.w >> 13, r = atomicAdd(&lhist[b], 1u);
            pairs[lbase[b] + r] = make_uint2(__float_as_uint(v.w), (u32)ix.w & 8191u);
        }
    }
}

// ---------------- K4: per-bin accumulate in LDS + streaming write ----------------
// 4096 blocks x 256 thr, 32 KB static LDS each.
__global__ __launch_bounds__(256) void k4_accum(const uint2* __restrict__ pairs,
                                                const u32* __restrict__ hist,
                                                const u32* __restrict__ start,
                                                float* __restrict__ out) {
    __shared__ float acc[BIN_FLOATS];
    int bin = blockIdx.x, tid = threadIdx.x;
    float4* a4 = (float4*)acc;
#pragma unroll
    for (int i = 0; i < 8; ++i) a4[tid + i * 256] = make_float4(0.f, 0.f, 0.f, 0.f);
    __syncthreads();
    u32 cnt = hist[bin], base = start[bin];
    for (u32 j = tid; j < cnt; j += 256) {
        uint2 p = pairs[base + j];
        atomicAdd(&acc[p.y], __uint_as_float(p.x));
    }
    __syncthreads();
    float4* o4 = (float4*)(out + ((size_t)bin << 13));
#pragma unroll
    for (int i = 0; i < 8; ++i) o4[tid + i * 256] = a4[tid + i * 256];
}

// ---------------- Fallback (ws too small): zero + device-atomic scatter ----------------
__global__ __launch_bounds__(256) void zero_out(float4* __restrict__ out) {
    int t = blockIdx.x * blockDim.x + threadIdx.x;
    out[t] = make_float4(0.f, 0.f, 0.f, 0.f);
}
__global__ __launch_bounds__(256) void scatter_atomic(const float4* __restrict__ in,
                                                      const int4* __restrict__ idx,
                                                      float* __restrict__ out) {
    int t = blockIdx.x * blockDim.x + threadIdx.x;
    float4 v = in[t];
    int4 ix = idx[t];
    float* obase = out + ((size_t)(t >> 18) << 22);
    atomicAdd(obase + ix.x, v.x);
    atomicAdd(obase + ix.y, v.y);
    atomicAdd(obase + ix.z, v.z);
    atomicAdd(obase + ix.w, v.w);
}

extern "C" void kernel_launch(void* const* d_in, const int* in_sizes, int n_in,
                              void* d_out, int out_size, void* d_ws, size_t ws_size,
                              hipStream_t stream) {
    const float4* val4 = (const float4*)d_in[0];
    const int4*   idx4 = (const int4*)d_in[1];
    float*        out  = (float*)d_out;

    const size_t needed = PAIR_BYTES + 3 * (size_t)NBINS * 4;
    if (ws_size < needed) {
        // Fallback: fast zero + device atomics (R1 structure).
        zero_out<<<(out_size / 4) / 256, 256, 0, stream>>>((float4*)d_out);
        scatter_atomic<<<(N / 4) / 256, 256, 0, stream>>>(val4, idx4, out);
        return;
    }

    uint2* pairs  = (uint2*)d_ws;
    u32*   hist   = (u32*)((char*)d_ws + PAIR_BYTES);
    u32*   cursor = hist + NBINS;
    u32*   start  = cursor + NBINS;

    hipMemsetAsync(hist, 0, NBINS * sizeof(u32), stream);
    k1_hist   <<<256, 512, 0, stream>>>(idx4, hist);
    k2_scan   <<<1, 64, 0, stream>>>(hist, start, cursor);
    k3_scatter<<<512, 512, 0, stream>>>(idx4, val4, cursor, pairs);
    k4_accum  <<<NBINS, 256, 0, stream>>>(pairs, hist, start, out);
}

// Round 3
// 277.747 us; speedup vs baseline: 2.0128x; 1.1817x over previous
//
#include <hip/hip_runtime.h>

// MaxUnPooling2DArgMax via two-phase binning (no device-scope fp32 atomics).
// B=8, in/batch=2^20, out/batch=2^22, N=2^23 pairs, out total 2^25 floats.
// Bin = 8192 floats (32 KB). 512 bins/batch, 4096 bins total.
// global_out = bin*8192 + off;  bin = (batch<<9) | (idx>>13);  off = idx&8191.
//
// R3: k3 rewritten as in-LDS counting sort so the pairs write is coalesced
// (R2 measured 196 MB written vs 67 MB ideal -> 8B scattered stores dirtying
// full 64B lines). Pairs are placed bin-sorted in a 64 KB LDS buffer, then
// flushed; consecutive LDS slots map to mostly-consecutive global addresses.

typedef unsigned int u32;

constexpr int N            = 1 << 23;   // input pairs
constexpr int NBINS        = 4096;
constexpr int BINS_PER_B   = 512;       // per batch
constexpr int BIN_FLOATS   = 8192;      // 32 KB
constexpr size_t PAIR_BYTES = (size_t)N * 8;

// ---------------- K1: histogram ----------------
// 256 blocks x 512 thr, chunk = 32768 pairs (32 blocks/batch), 16 int4/thread.
__global__ __launch_bounds__(512) void k1_hist(const int4* __restrict__ idx4,
                                               u32* __restrict__ hist) {
    __shared__ u32 lhist[BINS_PER_B];
    int tid = threadIdx.x;
    if (tid < BINS_PER_B) lhist[tid] = 0;
    __syncthreads();
    const int cb4 = blockIdx.x * 8192;              // 32768/4 int4 per block
    const u32 bb  = (u32)(blockIdx.x >> 5) << 9;    // batch * 512
#pragma unroll
    for (int i = 0; i < 16; ++i) {
        int4 v = idx4[cb4 + i * 512 + tid];
        atomicAdd(&lhist[(u32)v.x >> 13], 1u);
        atomicAdd(&lhist[(u32)v.y >> 13], 1u);
        atomicAdd(&lhist[(u32)v.z >> 13], 1u);
        atomicAdd(&lhist[(u32)v.w >> 13], 1u);
    }
    __syncthreads();
    if (tid < BINS_PER_B) {
        u32 c = lhist[tid];
        if (c) atomicAdd(&hist[bb + tid], c);
    }
}

// ---------------- K2: exclusive scan (1 wave) ----------------
__global__ void k2_scan(const u32* __restrict__ hist, u32* __restrict__ start,
                        u32* __restrict__ cursor) {
    int lane = threadIdx.x;  // blockDim = 64
    u32 base = 0;
    for (int c = 0; c < NBINS; c += 64) {
        u32 v = hist[c + lane];
        u32 s = v;
#pragma unroll
        for (int d = 1; d < 64; d <<= 1) {
            u32 t = __shfl_up(s, d);
            if (lane >= d) s += t;
        }
        u32 excl = base + (s - v);
        start[c + lane]  = excl;
        cursor[c + lane] = excl;
        base += __shfl(s, 63);
    }
}

// ---------------- K3: LDS counting sort -> coalesced pair flush ----------------
// 1024 blocks x 512 thr, chunk = 8192 pairs (128 blocks/batch), 16 pairs/thread.
// LDS: sorted 64 KB + 3*2 KB tables -> ~70 KB -> 2 blocks/CU.
__global__ __launch_bounds__(512) void k3_sort(const int4* __restrict__ idx4,
                                               const float4* __restrict__ val4,
                                               u32* __restrict__ cursor,
                                               uint2* __restrict__ pairs) {
    __shared__ u32 lhist[BINS_PER_B];    // hist, then placement counters
    __shared__ u32 lstart[BINS_PER_B];   // local exclusive scan
    __shared__ u32 lbase[BINS_PER_B];    // global base from cursor
    __shared__ u32 wsum[8];
    __shared__ uint2 sorted[8192];       // 64 KB, bin-sorted (val_bits, idx22)

    const int tid = threadIdx.x;
    lhist[tid] = 0;
    __syncthreads();

    const int cb4 = blockIdx.x * 2048;              // 8192/4 int4 per block
    const u32 bb  = (u32)(blockIdx.x >> 7) << 9;    // batch * 512

    int4   ix[4];
    float4 vv[4];
#pragma unroll
    for (int i = 0; i < 4; ++i) {
        ix[i] = idx4[cb4 + i * 512 + tid];
        vv[i] = val4[cb4 + i * 512 + tid];
    }
#pragma unroll
    for (int i = 0; i < 4; ++i) {
        atomicAdd(&lhist[(u32)ix[i].x >> 13], 1u);
        atomicAdd(&lhist[(u32)ix[i].y >> 13], 1u);
        atomicAdd(&lhist[(u32)ix[i].z >> 13], 1u);
        atomicAdd(&lhist[(u32)ix[i].w >> 13], 1u);
    }
    __syncthreads();

    // Block-wide exclusive scan of 512 bins (one bin per thread).
    const int lane = tid & 63, w = tid >> 6;
    u32 v = lhist[tid], s = v;
#pragma unroll
    for (int d = 1; d < 64; d <<= 1) {
        u32 t = __shfl_up(s, d);
        if (lane >= d) s += t;
    }
    if (lane == 63) wsum[w] = s;
    __syncthreads();
    if (tid == 0) {
        u32 acc = 0;
#pragma unroll
        for (int i = 0; i < 8; ++i) { u32 t = wsum[i]; wsum[i] = acc; acc += t; }
    }
    __syncthreads();
    const u32 excl = s - v + wsum[w];
    lstart[tid] = excl;
    lbase[tid]  = v ? atomicAdd(&cursor[bb + tid], v) : 0u;
    lhist[tid]  = 0;   // becomes placement counter
    __syncthreads();

    // Placement: scatter into LDS, sorted by bin. Keep full 22-bit idx in .y.
#pragma unroll
    for (int i = 0; i < 4; ++i) {
        {
            u32 b = (u32)ix[i].x >> 13, r = atomicAdd(&lhist[b], 1u);
            sorted[lstart[b] + r] = make_uint2(__float_as_uint(vv[i].x), (u32)ix[i].x);
        }
        {
            u32 b = (u32)ix[i].y >> 13, r = atomicAdd(&lhist[b], 1u);
            sorted[lstart[b] + r] = make_uint2(__float_as_uint(vv[i].y), (u32)ix[i].y);
        }
        {
            u32 b = (u32)ix[i].z >> 13, r = atomicAdd(&lhist[b], 1u);
            sorted[lstart[b] + r] = make_uint2(__float_as_uint(vv[i].z), (u32)ix[i].z);
        }
        {
            u32 b = (u32)ix[i].w >> 13, r = atomicAdd(&lhist[b], 1u);
            sorted[lstart[b] + r] = make_uint2(__float_as_uint(vv[i].w), (u32)ix[i].w);
        }
    }
    __syncthreads();

    // Flush: consecutive LDS slots -> mostly-consecutive global destinations.
#pragma unroll
    for (int k = 0; k < 16; ++k) {
        int j = k * 512 + tid;
        uint2 p = sorted[j];
        u32 b = p.y >> 13;
        u32 dst = lbase[b] + ((u32)j - lstart[b]);
        pairs[dst] = make_uint2(p.x, p.y & 8191u);
    }
}

// ---------------- K4: per-bin accumulate in LDS + streaming write ----------------
// 4096 blocks x 256 thr, 32 KB static LDS each.
__global__ __launch_bounds__(256) void k4_accum(const uint2* __restrict__ pairs,
                                                const u32* __restrict__ hist,
                                                const u32* __restrict__ start,
                                                float* __restrict__ out) {
    __shared__ float acc[BIN_FLOATS];
    int bin = blockIdx.x, tid = threadIdx.x;
    float4* a4 = (float4*)acc;
#pragma unroll
    for (int i = 0; i < 8; ++i) a4[tid + i * 256] = make_float4(0.f, 0.f, 0.f, 0.f);
    __syncthreads();
    u32 cnt = hist[bin], base = start[bin];
    for (u32 j = tid; j < cnt; j += 256) {
        uint2 p = pairs[base + j];
        atomicAdd(&acc[p.y], __uint_as_float(p.x));
    }
    __syncthreads();
    float4* o4 = (float4*)(out + ((size_t)bin << 13));
#pragma unroll
    for (int i = 0; i < 8; ++i) o4[tid + i * 256] = a4[tid + i * 256];
}

// ---------------- Fallback (ws too small): zero + device-atomic scatter ----------------
__global__ __launch_bounds__(256) void zero_out(float4* __restrict__ out) {
    int t = blockIdx.x * blockDim.x + threadIdx.x;
    out[t] = make_float4(0.f, 0.f, 0.f, 0.f);
}
__global__ __launch_bounds__(256) void scatter_atomic(const float4* __restrict__ in,
                                                      const int4* __restrict__ idx,
                                                      float* __restrict__ out) {
    int t = blockIdx.x * blockDim.x + threadIdx.x;
    float4 v = in[t];
    int4 ix = idx[t];
    float* obase = out + ((size_t)(t >> 18) << 22);
    atomicAdd(obase + ix.x, v.x);
    atomicAdd(obase + ix.y, v.y);
    atomicAdd(obase + ix.z, v.z);
    atomicAdd(obase + ix.w, v.w);
}

extern "C" void kernel_launch(void* const* d_in, const int* in_sizes, int n_in,
                              void* d_out, int out_size, void* d_ws, size_t ws_size,
                              hipStream_t stream) {
    const float4* val4 = (const float4*)d_in[0];
    const int4*   idx4 = (const int4*)d_in[1];
    float*        out  = (float*)d_out;

    const size_t needed = PAIR_BYTES + 3 * (size_t)NBINS * 4;
    if (ws_size < needed) {
        // Fallback: fast zero + device atomics (R1 structure).
        zero_out<<<(out_size / 4) / 256, 256, 0, stream>>>((float4*)d_out);
        scatter_atomic<<<(N / 4) / 256, 256, 0, stream>>>(val4, idx4, out);
        return;
    }

    uint2* pairs  = (uint2*)d_ws;
    u32*   hist   = (u32*)((char*)d_ws + PAIR_BYTES);
    u32*   cursor = hist + NBINS;
    u32*   start  = cursor + NBINS;

    hipMemsetAsync(hist, 0, NBINS * sizeof(u32), stream);
    k1_hist <<<256, 512, 0, stream>>>(idx4, hist);
    k2_scan <<<1, 64, 0, stream>>>(hist, start, cursor);
    k3_sort <<<1024, 512, 0, stream>>>(idx4, val4, cursor, pairs);
    k4_accum<<<NBINS, 256, 0, stream>>>(pairs, hist, start, out);
}

// Round 4
// 250.352 us; speedup vs baseline: 2.2330x; 1.1094x over previous
//
#include <hip/hip_runtime.h>

// MaxUnPooling2DArgMax via block-segmented binning sort (2 kernels, no
// global hist/scan/cursor, no device fp32 atomics).
// B=8, in/batch=2^20, out/batch=2^22, N=2^23 pairs, out total 2^25 floats.
// Bin = 8192 floats (32 KB). 512 bins/batch, 4096 bins total.
//
// kA: 1024 blocks x 8192 pairs. In-LDS counting sort by bin, flush to own
//     segment pairs[blk*8192..] (fully coalesced) + write local scan table
//     lstarts[blk*512+b] (2 MB, L2-resident for kB).
// kB: one block per bin. Read 128 segment descriptors, LDS-scan counts,
//     gather pairs via binary search, LDS atomicAdd accumulate, stream the
//     32 KB bin to d_out (also serves as the zero-init -> no memset).
//
// Measured context (R3): ~134 us of dur_us is fixed harness poison/restore
// fills; our controllable portion was ~143 us (k1~20 + k2~20 + k3~50 + k4~40).

typedef unsigned int u32;

constexpr int N            = 1 << 23;   // input pairs
constexpr int NBINS        = 4096;
constexpr int BINS_PER_B   = 512;       // per batch
constexpr int BIN_FLOATS   = 8192;      // 32 KB
constexpr int KA_BLOCKS    = 1024;
constexpr int PAIRS_PER_BLK = 8192;     // N / KA_BLOCKS
constexpr int BLKS_PER_BATCH = 128;     // KA_BLOCKS / 8
constexpr size_t PAIR_BYTES  = (size_t)N * 8;
constexpr size_t LSTART_BYTES = (size_t)KA_BLOCKS * BINS_PER_B * 4;

// ---------------- kA: LDS counting sort -> segmented coalesced flush ----------------
__global__ __launch_bounds__(512) void kA_sort(const int4* __restrict__ idx4,
                                               const float4* __restrict__ val4,
                                               uint2* __restrict__ pairs,
                                               u32* __restrict__ lstarts) {
    __shared__ u32 lhist[BINS_PER_B];    // hist, then placement counters
    __shared__ u32 lstart[BINS_PER_B];   // local exclusive scan
    __shared__ u32 wsum[8];
    __shared__ uint2 sorted[PAIRS_PER_BLK];  // 64 KB, bin-sorted (val_bits, idx22)

    const int tid = threadIdx.x;
    lhist[tid] = 0;
    __syncthreads();

    const int cb4 = blockIdx.x * (PAIRS_PER_BLK / 4);   // 2048 int4 per block

    int4   ix[4];
    float4 vv[4];
#pragma unroll
    for (int i = 0; i < 4; ++i) {
        ix[i] = idx4[cb4 + i * 512 + tid];
        vv[i] = val4[cb4 + i * 512 + tid];
    }
#pragma unroll
    for (int i = 0; i < 4; ++i) {
        atomicAdd(&lhist[(u32)ix[i].x >> 13], 1u);
        atomicAdd(&lhist[(u32)ix[i].y >> 13], 1u);
        atomicAdd(&lhist[(u32)ix[i].z >> 13], 1u);
        atomicAdd(&lhist[(u32)ix[i].w >> 13], 1u);
    }
    __syncthreads();

    // Block-wide exclusive scan of 512 bins (one bin per thread).
    const int lane = tid & 63, w = tid >> 6;
    u32 v = lhist[tid], s = v;
#pragma unroll
    for (int d = 1; d < 64; d <<= 1) {
        u32 t = __shfl_up(s, d);
        if (lane >= d) s += t;
    }
    if (lane == 63) wsum[w] = s;
    __syncthreads();
    if (tid == 0) {
        u32 acc = 0;
#pragma unroll
        for (int i = 0; i < 8; ++i) { u32 t = wsum[i]; wsum[i] = acc; acc += t; }
    }
    __syncthreads();
    const u32 excl = s - v + wsum[w];
    lstart[tid] = excl;
    lhist[tid]  = 0;   // becomes placement counter
    // Export local scan table (coalesced); kB derives counts from neighbors.
    lstarts[blockIdx.x * BINS_PER_B + tid] = excl;
    __syncthreads();

    // Placement: scatter into LDS, sorted by bin. Keep full 22-bit idx in .y.
#pragma unroll
    for (int i = 0; i < 4; ++i) {
        {
            u32 b = (u32)ix[i].x >> 13, r = atomicAdd(&lhist[b], 1u);
            sorted[lstart[b] + r] = make_uint2(__float_as_uint(vv[i].x), (u32)ix[i].x);
        }
        {
            u32 b = (u32)ix[i].y >> 13, r = atomicAdd(&lhist[b], 1u);
            sorted[lstart[b] + r] = make_uint2(__float_as_uint(vv[i].y), (u32)ix[i].y);
        }
        {
            u32 b = (u32)ix[i].z >> 13, r = atomicAdd(&lhist[b], 1u);
            sorted[lstart[b] + r] = make_uint2(__float_as_uint(vv[i].z), (u32)ix[i].z);
        }
        {
            u32 b = (u32)ix[i].w >> 13, r = atomicAdd(&lhist[b], 1u);
            sorted[lstart[b] + r] = make_uint2(__float_as_uint(vv[i].w), (u32)ix[i].w);
        }
    }
    __syncthreads();

    // Flush to own segment: perfectly coalesced uint2 stores.
    uint2* seg = pairs + (size_t)blockIdx.x * PAIRS_PER_BLK;
#pragma unroll
    for (int k = 0; k < 16; ++k) {
        int j = k * 512 + tid;
        uint2 p = sorted[j];
        seg[j] = make_uint2(p.x, p.y & 8191u);
    }
}

// ---------------- kB: per-bin gather + LDS accumulate + streaming write ----------------
__global__ __launch_bounds__(256) void kB_accum(const uint2* __restrict__ pairs,
                                                const u32* __restrict__ lstarts,
                                                float* __restrict__ out) {
    __shared__ float acc[BIN_FLOATS];          // 32 KB
    __shared__ u32 segStart[BLKS_PER_BATCH];   // global pair index of segment start
    __shared__ u32 scanB[BLKS_PER_BATCH + 1];  // exclusive scan of counts; [128]=M
    __shared__ u32 wtot;

    const int bin = blockIdx.x, tid = threadIdx.x;
    const int batch = bin >> 9, lb = bin & 511;
    const int blk0 = batch * BLKS_PER_BATCH;

    // Zero the accumulator.
    float4* a4 = (float4*)acc;
#pragma unroll
    for (int i = 0; i < 8; ++i) a4[tid + i * 256] = make_float4(0.f, 0.f, 0.f, 0.f);

    // Load 128 segment descriptors (strided 2 KB; lstarts is 2 MB -> L2-hot).
    u32 c = 0;
    if (tid < BLKS_PER_BATCH) {
        const u32 blk = blk0 + tid;
        const u32 ls = lstarts[blk * BINS_PER_B + lb];
        const u32 le = (lb == BINS_PER_B - 1) ? (u32)PAIRS_PER_BLK
                                              : lstarts[blk * BINS_PER_B + lb + 1];
        segStart[tid] = blk * PAIRS_PER_BLK + ls;
        c = le - ls;
    }
    // Scan the 128 counts (2 waves).
    const int lane = tid & 63, w = tid >> 6;
    u32 s = c;
#pragma unroll
    for (int d = 1; d < 64; d <<= 1) {
        u32 t = __shfl_up(s, d);
        if (lane >= d) s += t;
    }
    if (tid == 63) wtot = s;       // wave0 total
    __syncthreads();
    if (tid < BLKS_PER_BATCH) {
        u32 excl = s - c + (w == 1 ? wtot : 0u);
        scanB[tid] = excl;
        if (tid == BLKS_PER_BATCH - 1) scanB[BLKS_PER_BATCH] = excl + c;
    }
    __syncthreads();

    const u32 M = scanB[BLKS_PER_BATCH];
    for (u32 j = tid; j < M; j += 256) {
        // Binary search: largest seg with scanB[seg] <= j.
        u32 lo = 0, hi = BLKS_PER_BATCH - 1;
#pragma unroll
        for (int it = 0; it < 7; ++it) {
            u32 mid = (lo + hi + 1) >> 1;
            if (scanB[mid] <= j) lo = mid; else hi = mid - 1;
        }
        uint2 p = pairs[segStart[lo] + (j - scanB[lo])];
        atomicAdd(&acc[p.y], __uint_as_float(p.x));
    }
    __syncthreads();

    // Stream the bin out (coalesced float4); doubles as zero-init of d_out.
    float4* o4 = (float4*)(out + ((size_t)bin << 13));
#pragma unroll
    for (int i = 0; i < 8; ++i) o4[tid + i * 256] = a4[tid + i * 256];
}

// ---------------- Fallback (ws too small): zero + device-atomic scatter ----------------
__global__ __launch_bounds__(256) void zero_out(float4* __restrict__ out) {
    int t = blockIdx.x * blockDim.x + threadIdx.x;
    out[t] = make_float4(0.f, 0.f, 0.f, 0.f);
}
__global__ __launch_bounds__(256) void scatter_atomic(const float4* __restrict__ in,
                                                      const int4* __restrict__ idx,
                                                      float* __restrict__ out) {
    int t = blockIdx.x * blockDim.x + threadIdx.x;
    float4 v = in[t];
    int4 ix = idx[t];
    float* obase = out + ((size_t)(t >> 18) << 22);
    atomicAdd(obase + ix.x, v.x);
    atomicAdd(obase + ix.y, v.y);
    atomicAdd(obase + ix.z, v.z);
    atomicAdd(obase + ix.w, v.w);
}

extern "C" void kernel_launch(void* const* d_in, const int* in_sizes, int n_in,
                              void* d_out, int out_size, void* d_ws, size_t ws_size,
                              hipStream_t stream) {
    const float4* val4 = (const float4*)d_in[0];
    const int4*   idx4 = (const int4*)d_in[1];
    float*        out  = (float*)d_out;

    if (ws_size < PAIR_BYTES + LSTART_BYTES) {
        // Fallback: fast zero + device atomics (R1 structure).
        zero_out<<<(out_size / 4) / 256, 256, 0, stream>>>((float4*)d_out);
        scatter_atomic<<<(N / 4) / 256, 256, 0, stream>>>(val4, idx4, out);
        return;
    }

    uint2* pairs   = (uint2*)d_ws;
    u32*   lstarts = (u32*)((char*)d_ws + PAIR_BYTES);

    kA_sort <<<KA_BLOCKS, 512, 0, stream>>>(idx4, val4, pairs, lstarts);
    kB_accum<<<NBINS, 256, 0, stream>>>(pairs, lstarts, out);
}

// Round 6
// 250.348 us; speedup vs baseline: 2.2331x; 1.0000x over previous
//
#include <hip/hip_runtime.h>

// MaxUnPooling2DArgMax via block-sorted direct-slab binning (2 kernels).
// B=8, in/batch=2^20, out/batch=2^22, N=2^23 pairs, out total 2^25 floats.
// Bin = 8192 floats (32 KB of output). 512 bins/batch, 4096 bins total.
//
// R5/R6: each bin owns a fixed-capacity slab (CAP=3072 pairs; mean 2048,
// sigma ~45 -> 22-sigma headroom; drop-guard on overflow so validation would
// fail loudly). kA LDS-sorts 8192 pairs by bin (rank captured from the hist
// atomicAdd return -> no second LDS-atomic pass), reserves per-bin ranges
// with one device atomic per (block,bin), flushes 16-pair runs into slabs.
// kB then reads its slab fully contiguously (uint4), accumulates in LDS,
// and nontemporal-streams the 32 KB bin to d_out (doubles as zero-init).
// R6 fix: NT store uses ext_vector_type float4 (builtin rejects the HIP
// vector struct type).
// Fixed harness overhead measured ~124 us (ws/out poison + in restore).

typedef unsigned int u32;
typedef float nat_f4 __attribute__((ext_vector_type(4)));

constexpr int N             = 1 << 23;  // input pairs
constexpr int NBINS         = 4096;
constexpr int BINS_PER_B    = 512;      // per batch
constexpr int BIN_FLOATS    = 8192;     // 32 KB
constexpr int CAP           = 3072;     // slab slots per bin
constexpr int KA_BLOCKS     = 1024;
constexpr int PAIRS_PER_BLK = 8192;     // N / KA_BLOCKS
constexpr size_t SLAB_BYTES = (size_t)NBINS * CAP * 8;
constexpr size_t WS_NEEDED  = SLAB_BYTES + (size_t)NBINS * 4;

// ---------------- kA: LDS counting sort -> per-bin slab flush ----------------
__global__ __launch_bounds__(512, 4) void kA_sort(const int4* __restrict__ idx4,
                                                  const float4* __restrict__ val4,
                                                  uint2* __restrict__ slab,
                                                  u32* __restrict__ cursor) {
    __shared__ u32 lhist[BINS_PER_B];    // per-bin counts (preserved after hist)
    __shared__ u32 lstart[BINS_PER_B];   // local exclusive scan
    __shared__ u32 lbase[BINS_PER_B];    // global slab offset from cursor
    __shared__ u32 wsum[8];
    __shared__ uint2 sorted[PAIRS_PER_BLK];  // 64 KB, bin-sorted (val_bits, idx22)

    const int tid = threadIdx.x;
    lhist[tid] = 0;
    __syncthreads();

    const int cb4 = blockIdx.x * (PAIRS_PER_BLK / 4);   // 2048 int4 per block
    const u32 bb  = (u32)(blockIdx.x >> 7) << 9;        // batch * 512

    int4   ix[4];
    float4 vv[4];
    u32    rr[16];   // per-pair rank within its bin (from hist atomicAdd)
#pragma unroll
    for (int i = 0; i < 4; ++i) {
        ix[i] = idx4[cb4 + i * 512 + tid];
        vv[i] = val4[cb4 + i * 512 + tid];
    }
#pragma unroll
    for (int i = 0; i < 4; ++i) {
        rr[4 * i + 0] = atomicAdd(&lhist[(u32)ix[i].x >> 13], 1u);
        rr[4 * i + 1] = atomicAdd(&lhist[(u32)ix[i].y >> 13], 1u);
        rr[4 * i + 2] = atomicAdd(&lhist[(u32)ix[i].z >> 13], 1u);
        rr[4 * i + 3] = atomicAdd(&lhist[(u32)ix[i].w >> 13], 1u);
    }
    __syncthreads();

    // Block-wide exclusive scan of 512 bin counts (one bin per thread).
    const int lane = tid & 63, w = tid >> 6;
    const u32 v = lhist[tid];
    u32 s = v;
#pragma unroll
    for (int d = 1; d < 64; d <<= 1) {
        u32 t = __shfl_up(s, d);
        if (lane >= d) s += t;
    }
    if (lane == 63) wsum[w] = s;
    __syncthreads();
    if (tid == 0) {
        u32 acc = 0;
#pragma unroll
        for (int i = 0; i < 8; ++i) { u32 t = wsum[i]; wsum[i] = acc; acc += t; }
    }
    __syncthreads();
    lstart[tid] = s - v + wsum[w];
    // Reserve global slab range now; latency overlaps with placement below.
    lbase[tid] = v ? atomicAdd(&cursor[bb + tid], v) : 0u;
    __syncthreads();

    // Placement via precomputed ranks: plain LDS writes, no atomics.
#pragma unroll
    for (int i = 0; i < 4; ++i) {
        sorted[lstart[(u32)ix[i].x >> 13] + rr[4 * i + 0]] =
            make_uint2(__float_as_uint(vv[i].x), (u32)ix[i].x);
        sorted[lstart[(u32)ix[i].y >> 13] + rr[4 * i + 1]] =
            make_uint2(__float_as_uint(vv[i].y), (u32)ix[i].y);
        sorted[lstart[(u32)ix[i].z >> 13] + rr[4 * i + 2]] =
            make_uint2(__float_as_uint(vv[i].z), (u32)ix[i].z);
        sorted[lstart[(u32)ix[i].w >> 13] + rr[4 * i + 3]] =
            make_uint2(__float_as_uint(vv[i].w), (u32)ix[i].w);
    }
    __syncthreads();

    // Flush: 16-pair runs -> contiguous slab ranges (bin-major layout).
#pragma unroll
    for (int k = 0; k < 16; ++k) {
        int j = k * 512 + tid;
        uint2 p = sorted[j];
        u32 b = p.y >> 13;
        u32 r = lbase[b] + ((u32)j - lstart[b]);   // global rank within bin
        if (r < (u32)CAP)                          // overflow drop-guard
            slab[(size_t)(bb + b) * CAP + r] = make_uint2(p.x, p.y & 8191u);
    }
}

// ---------------- kB: contiguous slab read + LDS accumulate + NT stream ----------------
__global__ __launch_bounds__(512) void kB_accum(const uint2* __restrict__ slab,
                                                const u32* __restrict__ cursor,
                                                float* __restrict__ out) {
    __shared__ float acc[BIN_FLOATS];   // 32 KB
    const int bin = blockIdx.x, tid = threadIdx.x;

    nat_f4* a4 = (nat_f4*)acc;
#pragma unroll
    for (int i = 0; i < 4; ++i) a4[tid + i * 512] = (nat_f4)0.f;
    u32 cnt = cursor[bin];
    if (cnt > (u32)CAP) cnt = (u32)CAP;
    const uint2* seg = slab + (size_t)bin * CAP;
    __syncthreads();

    // Contiguous gather: 2 pairs per uint4 load.
    const uint4* seg4 = (const uint4*)seg;
    const u32 half = cnt >> 1;
    for (u32 j = tid; j < half; j += 512) {
        uint4 p = seg4[j];
        atomicAdd(&acc[p.y], __uint_as_float(p.x));
        atomicAdd(&acc[p.w], __uint_as_float(p.z));
    }
    if (tid == 0 && (cnt & 1u)) {
        uint2 p = seg[cnt - 1];
        atomicAdd(&acc[p.y], __uint_as_float(p.x));
    }
    __syncthreads();

    // Stream bin out (nontemporal: written once, never re-read).
    nat_f4* o4 = (nat_f4*)(out + ((size_t)bin << 13));
#pragma unroll
    for (int i = 0; i < 4; ++i)
        __builtin_nontemporal_store(a4[tid + i * 512], &o4[tid + i * 512]);
}

// ---------------- Fallback (ws too small): zero + device-atomic scatter ----------------
__global__ __launch_bounds__(256) void zero_out(float4* __restrict__ out) {
    int t = blockIdx.x * blockDim.x + threadIdx.x;
    out[t] = make_float4(0.f, 0.f, 0.f, 0.f);
}
__global__ __launch_bounds__(256) void scatter_atomic(const float4* __restrict__ in,
                                                      const int4* __restrict__ idx,
                                                      float* __restrict__ out) {
    int t = blockIdx.x * blockDim.x + threadIdx.x;
    float4 v = in[t];
    int4 ix = idx[t];
    float* obase = out + ((size_t)(t >> 18) << 22);
    atomicAdd(obase + ix.x, v.x);
    atomicAdd(obase + ix.y, v.y);
    atomicAdd(obase + ix.z, v.z);
    atomicAdd(obase + ix.w, v.w);
}

extern "C" void kernel_launch(void* const* d_in, const int* in_sizes, int n_in,
                              void* d_out, int out_size, void* d_ws, size_t ws_size,
                              hipStream_t stream) {
    const float4* val4 = (const float4*)d_in[0];
    const int4*   idx4 = (const int4*)d_in[1];
    float*        out  = (float*)d_out;

    if (ws_size < WS_NEEDED) {
        // Fallback: fast zero + device atomics (R1 structure).
        zero_out<<<(out_size / 4) / 256, 256, 0, stream>>>((float4*)d_out);
        scatter_atomic<<<(N / 4) / 256, 256, 0, stream>>>(val4, idx4, out);
        return;
    }

    uint2* slab   = (uint2*)d_ws;
    u32*   cursor = (u32*)((char*)d_ws + SLAB_BYTES);

    (void)hipMemsetAsync(cursor, 0, NBINS * sizeof(u32), stream);
    kA_sort <<<KA_BLOCKS, 512, 0, stream>>>(idx4, val4, slab, cursor);
    kB_accum<<<NBINS, 512, 0, stream>>>(slab, cursor, out);
}